// Round 1
// baseline (52.451 us; speedup 1.0000x reference)
//
#include <hip/hip_runtime.h>
#include <math.h>

// Per-row sum of squares. One block (256 threads) per (matrix, row).
// grid = 4 * 4096 blocks; block b: mat = b>>12, row = b&4095.
// Each row = 4096 f32 = 1024 float4; 256 threads -> 4 float4/thread, coalesced.
__global__ __launch_bounds__(256) void rowsumsq_kernel(
    const float* __restrict__ m0, const float* __restrict__ m1,
    const float* __restrict__ m2, const float* __restrict__ m3,
    float* __restrict__ row_ss /* [4*4096] */) {
    const int bid = blockIdx.x;
    const int mat = bid >> 12;
    const int row = bid & 4095;
    const float* in = (mat == 0) ? m0 : (mat == 1) ? m1 : (mat == 2) ? m2 : m3;

    const float4* p = reinterpret_cast<const float4*>(in + (size_t)row * 4096);
    float acc = 0.0f;
#pragma unroll
    for (int k = 0; k < 4; ++k) {
        float4 v = p[threadIdx.x + k * 256];
        acc = fmaf(v.x, v.x, acc);
        acc = fmaf(v.y, v.y, acc);
        acc = fmaf(v.z, v.z, acc);
        acc = fmaf(v.w, v.w, acc);
    }

    // wave64 reduce
#pragma unroll
    for (int off = 32; off > 0; off >>= 1) acc += __shfl_down(acc, off);

    __shared__ float s[4];
    if ((threadIdx.x & 63) == 0) s[threadIdx.x >> 6] = acc;
    __syncthreads();
    if (threadIdx.x == 0) row_ss[bid] = (s[0] + s[1]) + (s[2] + s[3]);
}

__device__ inline float nsq(float s2) {
    // sum(normalize(x)^2) = s2 / max(sqrt(s2), eps)^2  (F.normalize semantics)
    const float eps = 1e-12f;
    float m = fmaxf(sqrtf(s2), eps);
    return s2 / (m * m);
}

// Single block: combine 4*4096 row sums into the 3 scalars.
__global__ __launch_bounds__(256) void finalize_kernel(
    const float* __restrict__ row_ss, float* __restrict__ out) {
    const float* r2  = row_ss;              // uni_repr_rna
    const float* w2  = row_ss + 4096;       // uni_repr_wsi
    const float* rw2 = row_ss + 8192;       // uni_repr_rna_wsi
    const float* wr2 = row_ss + 12288;      // uni_repr_wsi_rna

    float sum_d1 = 0.0f, sum_d2 = 0.0f;
    for (int i = threadIdx.x; i < 4096; i += 256) {
        float a = r2[i], b = w2[i], c = rw2[i], d = wr2[i];
        // D1: product of normalized-sq-sums of rna, wsi
        sum_d1 += nsq(a) * nsq(b);
        // D2: shared = concat(wsi_rna, rna_wsi) -> ||shared||^2 = d + c
        //     single = concat(rna, wsi)         -> ||single||^2 = a + b
        sum_d2 += nsq(d + c) * nsq(a + b);
    }

#pragma unroll
    for (int off = 32; off > 0; off >>= 1) {
        sum_d1 += __shfl_down(sum_d1, off);
        sum_d2 += __shfl_down(sum_d2, off);
    }
    __shared__ float s1[4], s2[4];
    if ((threadIdx.x & 63) == 0) {
        s1[threadIdx.x >> 6] = sum_d1;
        s2[threadIdx.x >> 6] = sum_d2;
    }
    __syncthreads();
    if (threadIdx.x == 0) {
        float d1 = ((s1[0] + s1[1]) + (s1[2] + s1[3])) * (1.0f / 4096.0f);
        float d2 = ((s2[0] + s2[1]) + (s2[2] + s2[3])) * (1.0f / 4096.0f);
        out[0] = 0.5f * d2 + 0.5f * d1;  // loss
        out[1] = d1;                     // loss_D1
        out[2] = d2;                     // loss_D2
    }
}

extern "C" void kernel_launch(void* const* d_in, const int* in_sizes, int n_in,
                              void* d_out, int out_size, void* d_ws, size_t ws_size,
                              hipStream_t stream) {
    const float* rna    = (const float*)d_in[0];
    const float* wsi    = (const float*)d_in[1];
    const float* rnawsi = (const float*)d_in[2];
    const float* wsirna = (const float*)d_in[3];
    float* out = (float*)d_out;
    float* row_ss = (float*)d_ws;  // 4*4096 floats = 64 KB

    rowsumsq_kernel<<<4 * 4096, 256, 0, stream>>>(rna, wsi, rnawsi, wsirna, row_ss);
    finalize_kernel<<<1, 256, 0, stream>>>(row_ss, out);
}